// Round 11
// baseline (166.888 us; speedup 1.0000x reference)
//
#include <hip/hip_runtime.h>
#include <math.h>

typedef unsigned short u16;
typedef __attribute__((ext_vector_type(8))) short frag_ab;  // 8 bf16
typedef __attribute__((ext_vector_type(4))) float frag_cd;  // 4 fp32

#define BATCH 8
#define NN 128
#define FS 128
#define FV 64
#define NB 8
#define HID 64
#define ROUT 320
#define HSTRF 68    // hid fp32 LDS row stride (floats), layer-0 kernel
#define ASTR 136    // hidT bf16 LDS row stride (shorts): 272B rows, 16B-aligned, 2-way banks

// ---- ws: bf16 state arrays; s:[b][f][n], V:[b][f*3+c3][n], t:[b][g][n] (u16 offsets) ----
#define SZ_S (BATCH*FS*NN)
#define SZ_V (BATCH*FV*3*NN)
#define SZ_T (BATCH*FV*NN)

__device__ __forceinline__ float silu_f(float x){ return x * (1.0f/(1.0f + __expf(-x))); }

__device__ __forceinline__ u16 f2bf(float x){
  union { float f; unsigned int u; } v; v.f = x;
  unsigned int r = v.u + 0x7fffu + ((v.u >> 16) & 1u);
  return (u16)(r >> 16);
}
__device__ __forceinline__ float bf2f(u16 h){
  union { unsigned int u; float f; } v; v.u = ((unsigned int)h) << 16; return v.f;
}
__device__ __forceinline__ unsigned int scale2(unsigned int d, float v0, float v1){
  // d = two packed bf16; multiply lo by v0, hi by v1, repack (round-to-nearest-even)
  union { unsigned int u; float f; } lo, hi;
  lo.u = d << 16;
  hi.u = d & 0xffff0000u;
  float a = lo.f * v0;
  float b = hi.f * v1;
  return (unsigned int)f2bf(a) | ((unsigned int)f2bf(b) << 16);
}

// ---------------- Layer 0 (specialized: s=species uniform, V=0, t uniform) ----------------
__global__ __launch_bounds__(320) void layer0_kernel(
    const float* __restrict__ pos,
    const float* __restrict__ species,  // (128)
    const float* __restrict__ Wr1l,     // (8,64) layer0
    const float* __restrict__ Wr2,      // (2,64,320) fp32
    const float* __restrict__ Wsv,      // (2,128,64)
    const float* __restrict__ WmixSl,   // (192,128) layer0
    const float* __restrict__ WmixVl,   // (128,64) layer0
    u16* __restrict__ sOut,             // [b][f][n] bf16
    u16* __restrict__ vOut,             // [b][f*3+c3][n] bf16
    u16* __restrict__ tOut)             // [b][g][n] bf16
{
  const int tid = threadIdx.x;
  const int b   = blockIdx.x >> 7;
  const int k   = blockIdx.x & 127;

  __shared__ float hidF[128*HSTRF];
  __shared__ float vhx[128], vhy[128], vhz[128];
  __shared__ float colsum[4][64];
  __shared__ float aggS[128];
  __shared__ float aggV1[192];
  __shared__ float sNew[FS];
  __shared__ float t0L[64];

  const float* pb   = pos + b*NN*3;
  const float* Wr2l = Wr2;            // layer0 fp32 (64,320)

  if (tid < 256){
    const int i    = tid & 127;
    const int half = tid >> 7;
    float vx = pb[k*3+0]-pb[i*3+0];
    float vy = pb[k*3+1]-pb[i*3+1];
    float vz = pb[k*3+2]-pb[i*3+2];
    float r = sqrtf(vx*vx+vy*vy+vz*vz) + 1e-8f;
    float inv = 1.0f/r;
    if (half==0){ vhx[i]=vx*inv; vhy[i]=vy*inv; vhz[i]=vz*inv; }
    float u = r*0.2f;
    float env = 0.0f;
    if (u < 1.0f && i != k){
      float u2=u*u, u6=u2*u2*u2;
      env = 1.0f - 28.0f*u6 + 48.0f*u6*u - 21.0f*u6*u2;
    }
    float coef = 0.6324555320336759f * inv * env;
    float arg  = r * 0.6283185307179586f;
    float rb[NB];
    #pragma unroll
    for(int n=0;n<NB;n++) rb[n] = coef * __sinf(arg*(float)(n+1));
    #pragma unroll
    for(int jg=0;jg<8;jg++){
      const int jgg = half*8 + jg;
      float h0=0.f,h1=0.f,h2=0.f,h3=0.f;
      #pragma unroll
      for(int n=0;n<NB;n++){
        const float* wr = Wr1l + n*HID + jgg*4;
        float rn = rb[n];
        h0 = fmaf(rn, wr[0], h0);
        h1 = fmaf(rn, wr[1], h1);
        h2 = fmaf(rn, wr[2], h2);
        h3 = fmaf(rn, wr[3], h3);
      }
      float4 hh = make_float4(silu_f(h0), silu_f(h1), silu_f(h2), silu_f(h3));
      *(float4*)&hidF[i*HSTRF + jgg*4] = hh;
    }
  } else {
    const int g = tid - 256;   // 0..63
    float a0=0.f, a1=0.f;
    #pragma unroll 8
    for (int c=0; c<FS; c+=2){
      a0 = fmaf(species[c],   Wsv[c*FV+g],     a0);
      a1 = fmaf(species[c+1], Wsv[(c+1)*FV+g], a1);
    }
    t0L[g] = a0+a1;
  }
  __syncthreads();

  if (tid < 256){
    const int j   = tid & 63;
    const int var = tid >> 6;
    float a0 = 0.f, a1 = 0.f;
    if (var == 0){
      #pragma unroll 8
      for (int i=0;i<128;i+=2){ a0 += hidF[i*HSTRF + j]; a1 += hidF[(i+1)*HSTRF + j]; }
    } else {
      const float* wv = (var==1) ? vhx : (var==2) ? vhy : vhz;
      #pragma unroll 8
      for (int i=0;i<128;i+=2){
        a0 = fmaf(hidF[i*HSTRF + j],     wv[i],   a0);
        a1 = fmaf(hidF[(i+1)*HSTRF + j], wv[i+1], a1);
      }
    }
    colsum[var][j] = a0+a1;
  }
  __syncthreads();

  if (tid < 128){
    const int c = tid;
    float d0 = 0.f, d1 = 0.f;
    #pragma unroll 8
    for (int j=0;j<HID;j+=2){
      d0 = fmaf(colsum[0][j],   Wr2l[j*ROUT + c],     d0);
      d1 = fmaf(colsum[0][j+1], Wr2l[(j+1)*ROUT + c], d1);
    }
    aggS[c] = species[c] * (d0+d1) * (1.0f/128.0f);
  } else {
    const int idx = tid - 128;          // 0..191
    const int f = idx & 63, c3 = idx >> 6;
    float d0 = 0.f, d1 = 0.f;
    #pragma unroll 8
    for (int j=0;j<HID;j+=2){
      d0 = fmaf(colsum[1+c3][j],   Wr2l[j*ROUT + 192 + f],     d0);
      d1 = fmaf(colsum[1+c3][j+1], Wr2l[(j+1)*ROUT + 192 + f], d1);
    }
    aggV1[f*3+c3] = t0L[f] * (d0+d1) * (1.0f/128.0f);
  }
  __syncthreads();

  if (tid < FS){
    float a0=0.f, a1=0.f, a2=0.f, a3=0.f;
    #pragma unroll 8
    for (int cc=0; cc<128; cc+=4){
      a0 = fmaf(aggS[cc],   WmixSl[cc*FS+tid],     a0);
      a1 = fmaf(aggS[cc+1], WmixSl[(cc+1)*FS+tid], a1);
      a2 = fmaf(aggS[cc+2], WmixSl[(cc+2)*FS+tid], a2);
      a3 = fmaf(aggS[cc+3], WmixSl[(cc+3)*FS+tid], a3);
    }
    float sn = species[tid] + silu_f((a0+a1)+(a2+a3));
    sNew[tid] = sn;
    sOut[(b*FS+tid)*NN + k] = f2bf(sn);
  } else {
    const int o = tid - 128;            // 0..191
    const int g = o/3, c3 = o - g*3;
    float a0=0.f, a1=0.f;
    #pragma unroll 8
    for (int f=0; f<FV; f+=2){
      a0 = fmaf(aggV1[f*3+c3],     WmixVl[f*FV+g],     a0);
      a1 = fmaf(aggV1[(f+1)*3+c3], WmixVl[(f+1)*FV+g], a1);
    }
    vOut[(b*FV*3 + o)*NN + k] = f2bf(a0 + a1);
  }
  __syncthreads();
  if (tid < FV){
    const float* Wsv1 = Wsv + FS*FV;
    float a0=0.f, a1=0.f, a2=0.f, a3=0.f;
    #pragma unroll 8
    for (int f=0; f<FS; f+=4){
      a0 = fmaf(sNew[f],   Wsv1[f*FV+tid],     a0);
      a1 = fmaf(sNew[f+1], Wsv1[(f+1)*FV+tid], a1);
      a2 = fmaf(sNew[f+2], Wsv1[(f+2)*FV+tid], a2);
      a3 = fmaf(sNew[f+3], Wsv1[(f+3)*FV+tid], a3);
    }
    tOut[(b*FV+tid)*NN + k] = f2bf((a0+a1)+(a2+a3));
  }
}

// ---------------- Layer 1 (final): G = hidT @ B via MFMA; i is the K dim ----------------
// One block per (b,k); 512 threads = 8 waves. 44 jobs of 16 MFMA each, round-robin by wave.
// Job table: id<8: typeA (agg0a, B=s); id<20: typeB (agg0b, B=V_c3*vhat_c3);
//            id<32: typeC (agg1a, B=t*vhat_c3); else typeD (agg1b, B=V_c3).
__global__ __launch_bounds__(512) void layer_kernel(
    const float* __restrict__ pos,
    const u16*   __restrict__ sIn,    // [b][f][n] bf16
    const u16*   __restrict__ vIn,    // [b][f*3+c3][n] bf16
    const u16*   __restrict__ tIn,    // [b][g][n] bf16
    const float* __restrict__ Wr1l,   // (8,64) layer1
    const float* __restrict__ W2,     // (64,320) fp32 layer1
    const float* __restrict__ WmixSl, // (192,128)
    const float* __restrict__ WmixVl, // (128,64)
    const float* __restrict__ WoutS,
    const float* __restrict__ WoutV,
    float* __restrict__ outp)
{
  const int tid  = threadIdx.x;
  const int b    = blockIdx.x >> 7;
  const int k    = blockIdx.x & 127;
  const int w    = tid >> 6;
  const int lane = tid & 63;
  const int col  = lane & 15;
  const int quad = lane >> 4;

  __shared__ u16   A0[64*ASTR];        // hidT bf16: A0[j][i], 17.4 KB
  __shared__ float vhx[128], vhy[128], vhz[128];
  __shared__ float aggA[128];
  __shared__ float p0b[3][64], p1a[3][64], p1b[3][64];
  __shared__ float aggC[576];
  __shared__ float sPart[2][FS];
  __shared__ float sNew[FS];
  __shared__ float vNewL[192];
  __shared__ float comL[3];

  const float* pb = pos + b*NN*3;

  // ---- phase 0: tid = q*128+i; thread computes hid[i][q*16..q*16+16) -> A0[j][i] bf16 ----
  {
    const int i = tid & 127;
    const int q = tid >> 7;
    float vx = pb[k*3+0]-pb[i*3+0];
    float vy = pb[k*3+1]-pb[i*3+1];
    float vz = pb[k*3+2]-pb[i*3+2];
    float r = sqrtf(vx*vx+vy*vy+vz*vz) + 1e-8f;
    float inv = 1.0f/r;
    if (q==0){ vhx[i]=vx*inv; vhy[i]=vy*inv; vhz[i]=vz*inv; }
    float u = r*0.2f;
    float env = 0.0f;
    if (u < 1.0f && i != k){
      float u2=u*u, u6=u2*u2*u2;
      env = 1.0f - 28.0f*u6 + 48.0f*u6*u - 21.0f*u6*u2;
    }
    float coef = 0.6324555320336759f * inv * env;
    float arg  = r * 0.6283185307179586f;
    float rb[NB];
    #pragma unroll
    for(int n=0;n<NB;n++) rb[n] = coef * __sinf(arg*(float)(n+1));
    #pragma unroll
    for(int jg=0;jg<4;jg++){
      const int j0 = q*16 + jg*4;
      float h0=0.f,h1=0.f,h2=0.f,h3=0.f;
      #pragma unroll
      for(int n=0;n<NB;n++){
        const float* wr = Wr1l + n*HID + j0;
        float rn = rb[n];
        h0 = fmaf(rn, wr[0], h0);
        h1 = fmaf(rn, wr[1], h1);
        h2 = fmaf(rn, wr[2], h2);
        h3 = fmaf(rn, wr[3], h3);
      }
      A0[(j0+0)*ASTR + i] = f2bf(silu_f(h0));
      A0[(j0+1)*ASTR + i] = f2bf(silu_f(h1));
      A0[(j0+2)*ASTR + i] = f2bf(silu_f(h2));
      A0[(j0+3)*ASTR + i] = f2bf(silu_f(h3));
    }
    if (tid >= 509){
      const int c3 = tid - 509;
      float a0=0.f, a1=0.f;
      for (int n=0;n<NN;n+=2){ a0 += pb[n*3+c3]; a1 += pb[(n+1)*3+c3]; }
      comL[c3] = (a0+a1) * (1.0f/128.0f);
    }
  }
  __syncthreads();

  const u16* s16 = sIn + b*FS*NN;
  const u16* v16 = vIn + b*FV*3*NN;
  const u16* t16 = tIn + b*FV*NN;

  // ---- main: 44 jobs, each = 4 Mtiles x 4 Ktiles MFMA + W2-dot epilogue ----
  for (int id = w; id < 44; id += 8){
    int typ, nt, c3;
    if (id < 8){ typ=0; nt=id; c3=0; }
    else if (id < 20){ typ=1; c3=(id-8)>>2;  nt=(id-8)&3; }
    else if (id < 32){ typ=2; c3=(id-20)>>2; nt=(id-20)&3; }
    else            { typ=3; c3=(id-32)>>2; nt=(id-32)&3; }

    const u16* bptr; int cOut;
    if (typ==0){ cOut = nt*16+col;          bptr = s16 + cOut*NN; }
    else if (typ==1){ int f=nt*16+col; cOut = 128+f; bptr = v16 + (f*3+c3)*NN; }
    else if (typ==2){ int f=nt*16+col; cOut = 192+f; bptr = t16 + f*NN; }
    else            { int f=nt*16+col; cOut = 256+f; bptr = v16 + (f*3+c3)*NN; }

    frag_ab bfr[4];
    #pragma unroll
    for (int kt=0; kt<4; kt++)
      bfr[kt] = *(const frag_ab*)(bptr + kt*32 + quad*8);

    if (typ==1 || typ==2){
      const float* vh = (c3==0) ? vhx : (c3==1) ? vhy : vhz;
      #pragma unroll
      for (int kt=0; kt<4; kt++){
        const int ib = kt*32 + quad*8;
        float4 va = *(const float4*)&vh[ib];
        float4 vb4 = *(const float4*)&vh[ib+4];
        union { frag_ab f; unsigned int u[4]; } d;
        d.f = bfr[kt];
        d.u[0] = scale2(d.u[0], va.x,  va.y);
        d.u[1] = scale2(d.u[1], va.z,  va.w);
        d.u[2] = scale2(d.u[2], vb4.x, vb4.y);
        d.u[3] = scale2(d.u[3], vb4.z, vb4.w);
        bfr[kt] = d.f;
      }
    }

    float e = 0.f;
    #pragma unroll
    for (int mt=0; mt<4; mt++){
      frag_cd acc = {0.f,0.f,0.f,0.f};
      #pragma unroll
      for (int kt=0; kt<4; kt++){
        frag_ab af = *(const frag_ab*)&A0[(mt*16+col)*ASTR + kt*32 + quad*8];
        acc = __builtin_amdgcn_mfma_f32_16x16x32_bf16(af, bfr[kt], acc, 0,0,0);
      }
      const float* wrow = W2 + (mt*16 + quad*4)*ROUT + cOut;
      e = fmaf(acc[0], wrow[0],      e);
      e = fmaf(acc[1], wrow[ROUT],   e);
      e = fmaf(acc[2], wrow[2*ROUT], e);
      e = fmaf(acc[3], wrow[3*ROUT], e);
    }
    e += __shfl_xor(e, 16, 64);
    e += __shfl_xor(e, 32, 64);
    if (lane < 16){
      if (typ==0)      aggA[nt*16+lane]    = e;
      else if (typ==1) p0b[c3][nt*16+lane] = e;
      else if (typ==2) p1a[c3][nt*16+lane] = e;
      else             p1b[c3][nt*16+lane] = e;
    }
  }
  __syncthreads();

  // ---- assemble aggC[576]: [0..191]=agg0, [192+f*3+c3]=agg1a, [384+f*3+c3]=agg1b ----
  for (int t2=tid; t2<576; t2+=512){
    float v;
    if (t2 < 128) v = aggA[t2];
    else if (t2 < 192){ int f=t2-128; v = p0b[0][f]+p0b[1][f]+p0b[2][f]; }
    else if (t2 < 384){ int o=t2-192; int f=o/3, c3=o-f*3; v = p1a[c3][f]; }
    else              { int o=t2-384; int f=o/3, c3=o-f*3; v = p1b[c3][f]; }
    aggC[t2] = v * (1.0f/128.0f);
  }
  __syncthreads();

  // ---- E1 (disjoint): s-mix partials on tid<256; V-mix on tid 256..447 ----
  if (tid < 256){
    const int o = tid & 127, p = tid >> 7;
    const int c0 = p*96;
    float a0=0.f, a1=0.f, a2=0.f, a3=0.f;
    #pragma unroll 8
    for (int cc=c0; cc<c0+96; cc+=4){
      a0 = fmaf(aggC[cc],   WmixSl[cc*FS+o],     a0);
      a1 = fmaf(aggC[cc+1], WmixSl[(cc+1)*FS+o], a1);
      a2 = fmaf(aggC[cc+2], WmixSl[(cc+2)*FS+o], a2);
      a3 = fmaf(aggC[cc+3], WmixSl[(cc+3)*FS+o], a3);
    }
    sPart[p][o] = (a0+a1)+(a2+a3);
  } else if (tid < 448){
    const int o = tid - 256;            // 0..191
    const int g = o/3, c3 = o - g*3;
    float a0=0.f, a1=0.f, a2=0.f, a3=0.f;
    #pragma unroll 8
    for (int f=0; f<FV; f+=2){
      a0 = fmaf(aggC[192 + f*3+c3],     WmixVl[f*FV+g],        a0);
      a1 = fmaf(aggC[384 + f*3+c3],     WmixVl[(f+FV)*FV+g],   a1);
      a2 = fmaf(aggC[192 + (f+1)*3+c3], WmixVl[(f+1)*FV+g],    a2);
      a3 = fmaf(aggC[384 + (f+1)*3+c3], WmixVl[(f+1+FV)*FV+g], a3);
    }
    vNewL[o] = bf2f(v16[o*NN + k]) + (a0+a1)+(a2+a3);
  }
  __syncthreads();

  // ---- E2 (disjoint): s-finalize on tid<128; out_v on tid 128..319 ----
  if (tid < FS){
    float sk = bf2f(s16[tid*NN + k]);
    sNew[tid] = sk + silu_f(sPart[0][tid] + sPart[1][tid]);
  } else if (tid < 320){
    const int o = tid - 128;            // 0..191
    const int g = o/3, c3 = o - g*3;
    float a = comL[c3];
    #pragma unroll 8
    for (int f=0; f<FV; f++) a = fmaf(vNewL[f*3+c3], WoutV[f*FV+g], a);
    outp[(b*NN+k)*FV*3 + o] = a;
  }
  __syncthreads();

  // ---- E3: out_s on tid<128 ----
  if (tid < FS){
    float a0=0.f, a1=0.f, a2=0.f, a3=0.f;
    #pragma unroll 8
    for (int f=0; f<FS; f+=4){
      a0 = fmaf(sNew[f],   WoutS[f*FS+tid],     a0);
      a1 = fmaf(sNew[f+1], WoutS[(f+1)*FS+tid], a1);
      a2 = fmaf(sNew[f+2], WoutS[(f+2)*FS+tid], a2);
      a3 = fmaf(sNew[f+3], WoutS[(f+3)*FS+tid], a3);
    }
    outp[BATCH*NN*FV*3 + (b*NN+k)*FS + tid] = (a0+a1)+(a2+a3);
  }
}

extern "C" void kernel_launch(void* const* d_in, const int* in_sizes, int n_in,
                              void* d_out, int out_size, void* d_ws, size_t ws_size,
                              hipStream_t stream)
{
  const float* x       = (const float*)d_in[0];
  const float* species = (const float*)d_in[1];
  const float* Wr1     = (const float*)d_in[2];
  const float* Wr2     = (const float*)d_in[3];
  const float* Wsv     = (const float*)d_in[4];
  const float* WmixS   = (const float*)d_in[5];
  const float* WmixV   = (const float*)d_in[6];
  const float* WoutS   = (const float*)d_in[7];
  const float* WoutV   = (const float*)d_in[8];
  float* out = (float*)d_out;

  u16* s16 = (u16*)d_ws;
  u16* v16 = s16 + SZ_S;
  u16* t16 = v16 + SZ_V;

  // layer 0 (specialized) -> bf16 sB/vB/t1
  layer0_kernel<<<BATCH*NN, 320, 0, stream>>>(x, species, Wr1, Wr2, Wsv,
      WmixS, WmixV, s16, v16, t16);

  // layer 1 (final, GEMM-ified): writes d_out directly
  layer_kernel<<<BATCH*NN, 512, 0, stream>>>(x, s16, v16, t16,
      Wr1 + NB*HID, Wr2 + HID*ROUT, WmixS + 192*FS, WmixV + 128*FV,
      WoutS, WoutV, out);
}